// Round 4
// baseline (289.478 us; speedup 1.0000x reference)
//
#include <hip/hip_runtime.h>
#include <stdint.h>
#include <stddef.h>

// ---------------------------------------------------------------------------
// MaskedMultiHeadAttn: B=2, S=2048, D=1024, H=16, DK=64, fp32 in/out.
// scores = K·Q^T (roles swapped), NO 1/sqrt(dk) scale, causal+pad mask.
// R4: k_attn computes S^T (staged tile as A-frag, query regs as B-frag),
//     P^T -> PV A-frag via ds_bpermute (P LDS round-trip deleted),
//     unpaired bands (1024 blocks, 3 blocks/CU by LDS), LOG2E folded into
//     Q-projection, ballot fast-path padding mask.
// ---------------------------------------------------------------------------

typedef short bf16x8 __attribute__((ext_vector_type(8)));  // 8 bf16 = 4 VGPR
typedef float f32x4  __attribute__((ext_vector_type(4)));

__device__ __forceinline__ short f2bf(float f) {          // RNE
  union { float f; uint32_t u; } a; a.f = f;
  uint32_t r = a.u + 0x7fffu + ((a.u >> 16) & 1u);
  return (short)(r >> 16);
}
__device__ __forceinline__ float bf2f(short s) {
  union { uint32_t u; float f; } a; a.u = ((uint32_t)(uint16_t)s) << 16;
  return a.f;
}
__device__ __forceinline__ uint32_t pack2bf(float a, float b) {  // trunc pack
  union { float f; uint32_t u; } x, y; x.f = a; y.f = b;
  return (x.u >> 16) | (y.u & 0xffff0000u);
}
__device__ __forceinline__ float fast_exp2(float x) {
#if __has_builtin(__builtin_amdgcn_exp2f)
  return __builtin_amdgcn_exp2f(x);
#else
  return exp2f(x);
#endif
}
__device__ __forceinline__ void async16(const void* g, void* l) {
  __builtin_amdgcn_global_load_lds(
      (const __attribute__((address_space(1))) uint32_t*)g,
      (__attribute__((address_space(3))) uint32_t*)l, 16, 0, 0);
}
#define MFMA(a, b, c) __builtin_amdgcn_mfma_f32_16x16x32_bf16((a), (b), (c), 0, 0, 0)

// ---------------------------------------------------------------------------
// 1) split x (fp32) -> xhi, xlo bf16
// ---------------------------------------------------------------------------
__global__ void k_split_x(const float* __restrict__ x, short* __restrict__ xhi,
                          short* __restrict__ xlo) {
  int i = blockIdx.x * 256 + threadIdx.x;
  float4 v = ((const float4*)x)[i];
  short4 h, l;
  h.x = f2bf(v.x); l.x = f2bf(v.x - bf2f(h.x));
  h.y = f2bf(v.y); l.y = f2bf(v.y - bf2f(h.y));
  h.z = f2bf(v.z); l.z = f2bf(v.z - bf2f(h.z));
  h.w = f2bf(v.w); l.w = f2bf(v.w - bf2f(h.w));
  ((short4*)xhi)[i] = h;
  ((short4*)xlo)[i] = l;
}

// ---------------------------------------------------------------------------
// 2) W[k][n] fp32 -> Wt[n][k] bf16 (hi only). whi = 4 x 1M shorts (q,k,v,o).
// ---------------------------------------------------------------------------
__global__ void k_prep_w(const float* __restrict__ Wq, const float* __restrict__ Wk,
                         const float* __restrict__ Wv, const float* __restrict__ Wo,
                         short* __restrict__ whi) {
  __shared__ float T[64][65];
  int z = blockIdx.z;
  const float* W = (z == 0) ? Wq : (z == 1) ? Wk : (z == 2) ? Wv : Wo;
  int n0 = blockIdx.x * 64, k0 = blockIdx.y * 64;
  int t = threadIdx.x;
  int rr = t >> 4, cc = (t & 15) * 4;
#pragma unroll
  for (int it = 0; it < 4; ++it) {
    int row = rr + it * 16;
    float4 v = *(const float4*)&W[(size_t)(k0 + row) * 1024 + n0 + cc];
    T[row][cc] = v.x; T[row][cc + 1] = v.y; T[row][cc + 2] = v.z; T[row][cc + 3] = v.w;
  }
  __syncthreads();
  short* oh = whi + (size_t)z * 1048576;
#pragma unroll
  for (int it = 0; it < 4; ++it) {
    int nrow = rr + it * 16;
    short4 h4;
    h4.x = f2bf(T[cc + 0][nrow]);
    h4.y = f2bf(T[cc + 1][nrow]);
    h4.z = f2bf(T[cc + 2][nrow]);
    h4.w = f2bf(T[cc + 3][nrow]);
    *(short4*)&oh[(size_t)(n0 + nrow) * 1024 + k0 + cc] = h4;
  }
}

// ---------------------------------------------------------------------------
// 3) fused QKV projection GEMM (dbuf, single barrier/k-step).
//    Q-proj output is scaled by LOG2E (softmax base-2 folding).
// ---------------------------------------------------------------------------
__global__ __launch_bounds__(256, 3) void k_gemm_qkv(
    const short* __restrict__ xhi, const short* __restrict__ xlo,
    const short* __restrict__ whi,
    const float* __restrict__ bq, const float* __restrict__ bk,
    const float* __restrict__ bv,
    short* __restrict__ Qhi, short* __restrict__ Qlo,
    short* __restrict__ Khi, short* __restrict__ Klo,
    short* __restrict__ Vb) {
  __shared__ short AH[2][4096];
  __shared__ short AL[2][4096];
  __shared__ short BH[2][4096];
  int tid = threadIdx.x;
  int bx = blockIdx.x;                 // 0..23 ; z = bx>>3 : 0=Q 1=K 2=V
  int m0 = blockIdx.y * 128;
  int n0g = bx * 128;
  bool SPLIT = (bx < 16);
  int w = tid >> 6, lane = tid & 63, lr = lane & 15, lq = lane >> 4;
  int wm = w >> 1, wn = w & 1;
  f32x4 acc[4][4] = {};

  auto stage = [&](int ks, int pb) {
#pragma unroll
    for (int it = 0; it < 2; ++it) {
      int idx = it * 256 + tid;
      int row = idx >> 2, c = idx & 3;
      int cs = c ^ (row & 3);
      size_t ga = (size_t)(m0 + row) * 1024 + ks * 32 + cs * 8;
      async16(xhi + ga, &AH[pb][idx * 8]);
      if (SPLIT) async16(xlo + ga, &AL[pb][idx * 8]);
      size_t gb = (size_t)(n0g + row) * 1024 + ks * 32 + cs * 8;
      async16(whi + gb, &BH[pb][idx * 8]);
    }
  };

  stage(0, 0);
  int p = 0;
  int g = lq ^ (lr & 3);
  for (int ks = 0; ks < 32; ++ks) {
    __syncthreads();
    if (ks < 31) stage(ks + 1, p ^ 1);
    const bf16x8* A8 = (const bf16x8*)AH[p];
    const bf16x8* L8 = (const bf16x8*)AL[p];
    const bf16x8* B8 = (const bf16x8*)BH[p];
    bf16x8 af[4], al[4], bfr[4];
#pragma unroll
    for (int mt = 0; mt < 4; ++mt) af[mt] = A8[(wm * 64 + mt * 16 + lr) * 4 + g];
#pragma unroll
    for (int nt = 0; nt < 4; ++nt) bfr[nt] = B8[(wn * 64 + nt * 16 + lr) * 4 + g];
    if (SPLIT) {
#pragma unroll
      for (int mt = 0; mt < 4; ++mt) al[mt] = L8[(wm * 64 + mt * 16 + lr) * 4 + g];
    }
#pragma unroll
    for (int mt = 0; mt < 4; ++mt)
#pragma unroll
      for (int nt = 0; nt < 4; ++nt)
        acc[mt][nt] = MFMA(af[mt], bfr[nt], acc[mt][nt]);
    if (SPLIT) {
#pragma unroll
      for (int mt = 0; mt < 4; ++mt)
#pragma unroll
        for (int nt = 0; nt < 4; ++nt)
          acc[mt][nt] = MFMA(al[mt], bfr[nt], acc[mt][nt]);
    }
    p ^= 1;
  }

  int z = bx >> 3;
  const float LOG2E = 1.44269504f;
  const float* bias = (z == 0) ? bq : (z == 1) ? bk : bv;
  short* Ch = (z == 0) ? Qhi : (z == 1) ? Khi : Vb;
  short* Cl = (z == 0) ? Qlo : Klo;
#pragma unroll
  for (int nt = 0; nt < 4; ++nt) {
    int colg = (n0g & 1023) + wn * 64 + nt * 16 + lr;
    float bvv = bias[colg];
#pragma unroll
    for (int mt = 0; mt < 4; ++mt)
#pragma unroll
      for (int r = 0; r < 4; ++r) {
        int row = m0 + wm * 64 + mt * 16 + lq * 4 + r;
        float v = acc[mt][nt][r] + bvv;
        if (z == 0) v *= LOG2E;       // base-2 softmax folding
        size_t o = (size_t)row * 1024 + colg;
        if (z < 2) {
          short hh = f2bf(v);
          Ch[o] = hh;
          Cl[o] = f2bf(v - bf2f(hh));
        } else {
          Ch[o] = f2bf(v);
        }
      }
  }
}

// ---------------------------------------------------------------------------
// 4) O-projection GEMM: out = Obuf @ Wo^T + bo, fp32 out.
// ---------------------------------------------------------------------------
__global__ __launch_bounds__(256, 2) void k_gemm_o(
    const short* __restrict__ Ab, const short* __restrict__ Bb,
    const float* __restrict__ bias, float* __restrict__ Cf) {
  __shared__ short AH[2][4096];
  __shared__ short BH[2][4096];
  int tid = threadIdx.x;
  int m0 = blockIdx.y * 128, n0 = blockIdx.x * 128;
  int w = tid >> 6, lane = tid & 63, lr = lane & 15, lq = lane >> 4;
  int wm = w >> 1, wn = w & 1;
  f32x4 acc[4][4] = {};

  auto stage = [&](int ks, int pb) {
#pragma unroll
    for (int it = 0; it < 2; ++it) {
      int idx = it * 256 + tid;
      int row = idx >> 2, c = idx & 3;
      int cs = c ^ (row & 3);
      async16(Ab + (size_t)(m0 + row) * 1024 + ks * 32 + cs * 8, &AH[pb][idx * 8]);
      async16(Bb + (size_t)(n0 + row) * 1024 + ks * 32 + cs * 8, &BH[pb][idx * 8]);
    }
  };

  stage(0, 0);
  int p = 0;
  int g = lq ^ (lr & 3);
  for (int ks = 0; ks < 32; ++ks) {
    __syncthreads();
    if (ks < 31) stage(ks + 1, p ^ 1);
    const bf16x8* A8 = (const bf16x8*)AH[p];
    const bf16x8* B8 = (const bf16x8*)BH[p];
    bf16x8 af[4], bfr[4];
#pragma unroll
    for (int mt = 0; mt < 4; ++mt) af[mt] = A8[(wm * 64 + mt * 16 + lr) * 4 + g];
#pragma unroll
    for (int nt = 0; nt < 4; ++nt) bfr[nt] = B8[(wn * 64 + nt * 16 + lr) * 4 + g];
#pragma unroll
    for (int mt = 0; mt < 4; ++mt)
#pragma unroll
      for (int nt = 0; nt < 4; ++nt)
        acc[mt][nt] = MFMA(af[mt], bfr[nt], acc[mt][nt]);
    p ^= 1;
  }
#pragma unroll
  for (int nt = 0; nt < 4; ++nt) {
    int col = n0 + wn * 64 + nt * 16 + lr;
    float bvv = bias[col];
#pragma unroll
    for (int mt = 0; mt < 4; ++mt)
#pragma unroll
      for (int r = 0; r < 4; ++r) {
        int row = m0 + wm * 64 + mt * 16 + lq * 4 + r;
        Cf[(size_t)row * 1024 + col] = acc[mt][nt][r] + bvv;
      }
  }
}

// ---------------------------------------------------------------------------
// 5) transpose V: Vb [B*S][1024] bf16 -> Vt [(b*16+h)*64+d][s]
// ---------------------------------------------------------------------------
__global__ void k_vt(const short* __restrict__ Vb, short* __restrict__ Vt) {
  __shared__ short T[64][72];
  int s0 = blockIdx.x * 64;
  int bh = blockIdx.y, b = bh >> 4, h = bh & 15;
  int tid = threadIdx.x;
#pragma unroll
  for (int it = 0; it < 2; ++it) {
    int idx = it * 256 + tid, r = idx >> 3, c = idx & 7;
    bf16x8 v = *(const bf16x8*)(Vb + (size_t)(b * 2048 + s0 + r) * 1024 + h * 64 + c * 8);
    *(bf16x8*)&T[r][c * 8] = v;
  }
  __syncthreads();
#pragma unroll
  for (int it = 0; it < 2; ++it) {
    int idx = it * 256 + tid, d = idx >> 3, sc = idx & 7;
    bf16x8 vv;
#pragma unroll
    for (int j = 0; j < 8; ++j) vv[j] = T[sc * 8 + j][d];
    *(bf16x8*)(Vt + (size_t)(bh * 64 + d) * 2048 + s0 + sc * 8) = vv;
  }
}

// ---------------------------------------------------------------------------
// 6) flash attention, one 64-row band per block (1024 blocks, longest first).
//    S^T form: staged keys-role tile = A-frag, query regs = B-frag.
//    P^T -> PV A-frag via ds_bpermute (no P LDS). No online softmax.
//    LDS: 3 x 16KB dbuf tiles = 48KB -> 3 blocks/CU.
// ---------------------------------------------------------------------------
__global__ __launch_bounds__(256, 3) void k_attn(
    const short* __restrict__ Khi, const short* __restrict__ Klo,
    const short* __restrict__ Qhi, const short* __restrict__ Qlo,
    const short* __restrict__ Vt, const int* __restrict__ amask,
    short* __restrict__ Obuf) {
  __shared__ short QH[2][4096];     // keys-role hi: [j 64][d 64] swizzled
  __shared__ short QL[2][4096];     // keys-role lo
  __shared__ short VS[2][4096];     // V^T tile: [d 64][j 64] swizzled
  int tid = threadIdx.x;
  int band = 31 - blockIdx.x;       // longest bands dispatch first
  int bh = blockIdx.y, b = bh >> 4, h = bh & 15;
  int w = tid >> 6, lane = tid & 63, lr = lane & 15, lq = lane >> 4;
  int i0 = band * 64;

  // query-role fragments (K-proj rows), hi+lo, registers. B-frag: n=lr row.
  bf16x8 kh[2], kl[2];
  {
    size_t ra = ((size_t)(b * 2048 + i0 + w * 16 + lr)) * 1024 + h * 64;
#pragma unroll
    for (int ks = 0; ks < 2; ++ks) {
      kh[ks] = *(const bf16x8*)(Khi + ra + ks * 32 + lq * 8);
      kl[ks] = *(const bf16x8*)(Klo + ra + ks * 32 + lq * 8);
    }
  }

  f32x4 O[4] = {};
  float lsacc = 0.f;
  int iq = i0 + w * 16 + lr;        // this lane's query row (global s)
  int baddr0 = (((lq & 1) * 2) * 16 + lr) * 4;   // bpermute byte addrs
  int baddr1 = baddr0 + 64;

  auto stage = [&](int jt, int pb) {
    int j0 = jt * 64;
#pragma unroll
    for (int it = 0; it < 2; ++it) {
      int idx = it * 256 + tid;
      int rr = idx >> 3, c = idx & 7;
      int cs = c ^ (rr & 7);        // XOR swizzle via global src granule
      size_t gq = ((size_t)(b * 2048 + j0 + rr)) * 1024 + h * 64 + cs * 8;
      async16(Qhi + gq, &QH[pb][idx * 8]);
      async16(Qlo + gq, &QL[pb][idx * 8]);
      size_t gv = ((size_t)(bh * 64 + rr)) * 2048 + j0 + cs * 8;
      async16(Vt + gv, &VS[pb][idx * 8]);
    }
  };

  stage(0, 0);
  int p = 0;
  for (int jt = 0; jt <= band; ++jt) {
    __syncthreads();                // buf p ready; buf p^1 free
    if (jt < band) stage(jt + 1, p ^ 1);
    int j0 = jt * 64;
    const bf16x8* Q8 = (const bf16x8*)QH[p];
    const bf16x8* L8 = (const bf16x8*)QL[p];
    const bf16x8* V8 = (const bf16x8*)VS[p];

    // padding-mask fast path: one coalesced load + ballot per tile
    int av = amask[b * 2048 + j0 + lane];
    unsigned long long bal = __ballot(av != 0);
    bool allv = (bal == ~0ull);

    // S^T: rows j (4 mt), cols i (16 queries). 3-term split.
    f32x4 s[4] = {};
#pragma unroll
    for (int mt = 0; mt < 4; ++mt) {
      int row = mt * 16 + lr;
#pragma unroll
      for (int ks = 0; ks < 2; ++ks) {
        int gi = row * 8 + ((ks * 4 + lq) ^ (row & 7));
        bf16x8 qa = Q8[gi];
        bf16x8 la = L8[gi];
        s[mt] = MFMA(qa, kh[ks], s[mt]);
        s[mt] = MFMA(la, kh[ks], s[mt]);
        s[mt] = MFMA(qa, kl[ks], s[mt]);
      }
    }

    // exp2 (scores pre-scaled by LOG2E), causal/pad mask, row-sum, pack
    float pv[4][4];
#pragma unroll
    for (int mt = 0; mt < 4; ++mt)
#pragma unroll
      for (int r = 0; r < 4; ++r)
        pv[mt][r] = fast_exp2(s[mt][r]);
    if (jt == band) {               // diagonal tile: j > i masked
#pragma unroll
      for (int mt = 0; mt < 4; ++mt)
#pragma unroll
        for (int r = 0; r < 4; ++r)
          if (j0 + mt * 16 + lq * 4 + r > iq) pv[mt][r] = 0.f;
    }
    if (!allv) {                    // rare slow path: per-bit padding mask
#pragma unroll
      for (int mt = 0; mt < 4; ++mt)
#pragma unroll
        for (int r = 0; r < 4; ++r)
          if (!((bal >> (mt * 16 + lq * 4 + r)) & 1)) pv[mt][r] = 0.f;
    }
    uint32_t pd[4][2];
#pragma unroll
    for (int mt = 0; mt < 4; ++mt) {
      lsacc += (pv[mt][0] + pv[mt][1]) + (pv[mt][2] + pv[mt][3]);
      pd[mt][0] = pack2bf(pv[mt][0], pv[mt][1]);
      pd[mt][1] = pack2bf(pv[mt][2], pv[mt][3]);
    }

    // PV: A-frag(P) built via bpermute; B-frag = V^T rows (d).
#pragma unroll
    for (int k2 = 0; k2 < 2; ++k2) {
      union { int i[4]; bf16x8 v; } pa;
#pragma unroll
      for (int dd = 0; dd < 4; ++dd) {
        int addr = (dd >> 1) ? baddr1 : baddr0;
        int v0 = __builtin_amdgcn_ds_bpermute(addr, (int)pd[k2 * 2 + 0][dd & 1]);
        int v1 = __builtin_amdgcn_ds_bpermute(addr, (int)pd[k2 * 2 + 1][dd & 1]);
        pa.i[dd] = (lq >> 1) ? v1 : v0;
      }
#pragma unroll
      for (int nt = 0; nt < 4; ++nt) {
        int row = nt * 16 + lr;
        bf16x8 vb = V8[row * 8 + ((k2 * 4 + lq) ^ (row & 7))];
        O[nt] = MFMA(pa.v, vb, O[nt]);
      }
    }
    p ^= 1;
  }

  // epilogue: reduce ls over lq (cols i=lr), redistribute to C rows, store
  float t = lsacc;
  t += __shfl_xor(t, 16);
  t += __shfl_xor(t, 32);
  float inv[4];
#pragma unroll
  for (int r = 0; r < 4; ++r) inv[r] = 1.0f / __shfl(t, lq * 4 + r, 64);
#pragma unroll
  for (int nt = 0; nt < 4; ++nt)
#pragma unroll
    for (int r = 0; r < 4; ++r) {
      int row = b * 2048 + i0 + w * 16 + lq * 4 + r;
      int col = h * 64 + nt * 16 + lr;
      Obuf[(size_t)row * 1024 + col] = f2bf(O[nt][r] * inv[r]);
    }
}

// ---------------------------------------------------------------------------
// launcher
// ---------------------------------------------------------------------------
extern "C" void kernel_launch(void* const* d_in, const int* in_sizes, int n_in,
                              void* d_out, int out_size, void* d_ws, size_t ws_size,
                              hipStream_t stream) {
  const float* x  = (const float*)d_in[0];
  const int* amask = (const int*)d_in[1];
  const float* Wq = (const float*)d_in[2];
  const float* bq = (const float*)d_in[3];
  const float* Wk = (const float*)d_in[4];
  const float* bk = (const float*)d_in[5];
  const float* Wv = (const float*)d_in[6];
  const float* bv = (const float*)d_in[7];
  const float* Wo = (const float*)d_in[8];
  const float* bo = (const float*)d_in[9];

  char* ws = (char*)d_ws;
  const size_t MB = 1024 * 1024;
  short* xhi = (short*)(ws);             // reused as Vt after GEMMs
  short* xlo = (short*)(ws + 8 * MB);    // reused as Obuf after GEMMs
  short* whi = (short*)(ws + 16 * MB);   // 4 x 1M shorts (q,k,v,o), [n][k]
  short* Qhi = (short*)(ws + 28 * MB);
  short* Qlo = (short*)(ws + 36 * MB);
  short* Khi = (short*)(ws + 44 * MB);
  short* Klo = (short*)(ws + 52 * MB);
  short* Vb  = (short*)(ws + 60 * MB);   // total 68MB
  short* Vt   = xhi;
  short* Obuf = xlo;

  k_split_x<<<4096, 256, 0, stream>>>(x, xhi, xlo);
  k_prep_w<<<dim3(16, 16, 4), 256, 0, stream>>>(Wq, Wk, Wv, Wo, whi);

  k_gemm_qkv<<<dim3(24, 32), 256, 0, stream>>>(xhi, xlo, whi, bq, bk, bv,
                                               Qhi, Qlo, Khi, Klo, Vb);
  k_vt<<<dim3(32, 32), 256, 0, stream>>>(Vb, Vt);
  k_attn<<<dim3(32, 32), 256, 0, stream>>>(Khi, Klo, Qhi, Qlo, Vt, amask, Obuf);
  k_gemm_o<<<dim3(8, 32), 256, 0, stream>>>(Obuf, whi + 3 * 1048576, bo, (float*)d_out);
}